// Round 5
// baseline (659.663 us; speedup 1.0000x reference)
//
#include <hip/hip_runtime.h>
#include <stdint.h>

// Chebyshev GCN: out[b,n,o,t] = relu( sum_{k,c,m} cheb[k,m,n]*STDG[b,m,n]*x[b,m,c,t]*theta[k,c,o] )
// Per b:  C[n, j] = relu( sum_p A[p,n] * Y[p,j] ),  p=(k,m) in [0,3072), j=o*24+t
//   A[p,n] = cheb[k,m,n]*STDG[b,m,n]          (kprepA: bf16, stored [bb][n][p])
//   Y[p,j] = sum_c theta[k,c,o]*x[b,m,c,t]    (kprepY: bf16, written transposed [bb][j][p])
// Round-5 (bisect + de-risked wins over the validated round-3 baseline):
//  - kprepY: BODY IS VERBATIM ROUND-3 (validated, absmax 8.0). Only the grid mapping changed:
//    (ms on blockIdx.x, jb on blockIdx.y) so linear id = ms + jb*32 -> XCD = ms&7: all 8
//    jb-siblings sharing one 196 KB x-slab pin to ONE XCD's L2 (round 3 spread them over all
//    8 XCDs -> 394 MB fetch for a 101 MB x footprint).
//  - kprepA: round-4 v2 kept (cheb staged once for all 3 k, b-loop inside, 256 blocks);
//    audited byte-equivalent to round-3 output. If THIS round fails, kprepA v2 was the
//    round-4 bug -> revert next round.
//  - kgemm: untouched (validated).

#define BB   16
#define NN   1024
#define CIN  64
#define TT   24
#define KCH  3
#define COUT 64
#define PP   (KCH*NN)    // 3072 contraction length
#define JJ   (COUT*TT)   // 1536 output columns per n

typedef __attribute__((ext_vector_type(4))) float f32x4;
typedef __attribute__((ext_vector_type(8))) short bf16x8;

typedef __attribute__((address_space(1))) const unsigned int* gas_cuintp;
typedef __attribute__((address_space(3))) unsigned int* las_uintp;

static __device__ __forceinline__ unsigned short f2bf(float f){
  union { float f; unsigned u; } v; v.f = f;
  unsigned r = v.u + 0x7fffu + ((v.u >> 16) & 1u);   // round-to-nearest-even
  return (unsigned short)(r >> 16);
}

// ---------------- K0: A-prep  (masked = cheb*STDG, bf16, transpose to [bb][n][p]) ----------------
// Grid (16 nt, 16 mt) = 256 blocks; chebT (3 k) staged once; loop over b inside.
__global__ __launch_bounds__(256) void kprepA(const float* __restrict__ cheb,
                                              const float* __restrict__ stdg,
                                              unsigned short* __restrict__ Ah,
                                              int b0, int nb){
  int nt = blockIdx.x;             // 16 n-tiles of 64
  int mt = blockIdx.y;             // 16 m-tiles of 64
  __shared__ float ct[3][64][65];  // chebT [k][n][m], padded (49.9 KB)
  __shared__ float st[64][65];     // stdgT [n][m], padded (16.6 KB)
  int tid = threadIdx.x;
  int rm = tid >> 2;               // m row 0..63 (staging)
  int nc = (tid & 3) << 4;         // n col group
  #pragma unroll
  for (int k = 0; k < 3; k++){
    const float* cp = cheb + ((size_t)(k*NN + mt*64 + rm))*NN + nt*64 + nc;
    #pragma unroll
    for (int i = 0; i < 16; i += 4){
      f32x4 cv = *(const f32x4*)(cp + i);
      #pragma unroll
      for (int q = 0; q < 4; q++) ct[k][nc + i + q][rm] = cv[q];
    }
  }
  int rn = tid >> 2;               // n row 0..63 (compute)
  int mc = (tid & 3) << 4;         // m col group
  for (int bb = 0; bb < nb; bb++){
    int b = b0 + bb;
    __syncthreads();               // ct ready (first iter) / st consumed (later)
    const float* sp = stdg + ((size_t)(b*NN + mt*64 + rm))*NN + nt*64 + nc;
    #pragma unroll
    for (int i = 0; i < 16; i += 4){
      f32x4 sv = *(const f32x4*)(sp + i);
      #pragma unroll
      for (int q = 0; q < 4; q++) st[nc + i + q][rm] = sv[q];
    }
    __syncthreads();
    #pragma unroll
    for (int k = 0; k < 3; k++){
      union { unsigned short s[16]; uint4 v[2]; } hb;
      #pragma unroll
      for (int i = 0; i < 16; i++) hb.s[i] = f2bf(ct[k][rn][mc + i] * st[rn][mc + i]);
      size_t ob = ((size_t)(bb*NN + nt*64 + rn))*PP + (size_t)k*NN + mt*64 + mc;
      *(uint4*)(Ah + ob)     = hb.v[0];
      *(uint4*)(Ah + ob + 8) = hb.v[1];
    }
  }
}

// ---------------- K1: Y-prep fused with transpose -> writes [bb][j][p] directly ----------------
// BODY VERBATIM ROUND-3 (validated). Grid mapping swapped: ms = blockIdx.x, jb = blockIdx.y
// so the 8 jb-siblings of one (ms,bb) x-slab land on ONE XCD (linear id = ms + jb*32 + bb*256).
// 256 threads: (m = tid>>3 within 32-m slab, o = tid&7 within 8-o block).
// LDS: x chunk [32m][8c][24t] f32 (m-stride 196), theta [3][64][8],
//      ytile [192 j][32 p] bf16 as 4x16B chunks/row with XOR swizzle.
__global__ __launch_bounds__(256) void kprepY(const float* __restrict__ x,
                                              const float* __restrict__ theta,
                                              unsigned short* __restrict__ Yt,
                                              int b0){
  int ms = blockIdx.x;             // 32 m-slabs of 32   (was blockIdx.y in round 3)
  int jb = blockIdx.y;             // 8 o-blocks of 8    (was blockIdx.x in round 3)
  int bb = blockIdx.z;
  int b  = b0 + bb;
  __shared__ float xs[32*196];             // 25088 B (per-m stride 196 floats, 192 used)
  __shared__ float ths[3*64*8];            // 6144 B
  __shared__ unsigned short ytile[192*32]; // 12288 B
  int tid = threadIdx.x;
  int mi = tid >> 3, oi = tid & 7;

  // stage theta slice [3][64 c][8 o]
  for (int i = tid; i < 3*64*8; i += 256){
    int k = i >> 9, rem = i & 511;
    int c = rem >> 3, o = rem & 7;
    ths[i] = theta[k*(CIN*COUT) + c*COUT + jb*8 + o];
  }

  float acc0[24], acc1[24], acc2[24];
  #pragma unroll
  for (int t = 0; t < 24; t++){ acc0[t]=0.f; acc1[t]=0.f; acc2[t]=0.f; }

  const f32x4* xg4 = (const f32x4*)(x + ((size_t)(b*NN + ms*32))*CIN*TT);
  for (int cc = 0; cc < 8; cc++){
    __syncthreads();               // first iter: theta ready; later: xs consumed
    // stage x chunk: per m, floats [cc*192, cc*192+192) = c in [cc*8, cc*8+8), all t
    for (int i4 = tid; i4 < 32*48; i4 += 256){
      int m = i4 / 48, r = i4 - m*48;
      *(f32x4*)&xs[m*196 + r*4] = xg4[m*384 + cc*48 + r];
    }
    __syncthreads();
    for (int c8 = 0; c8 < 8; c8++){
      float xv[24];
      #pragma unroll
      for (int q = 0; q < 6; q++) *(f32x4*)&xv[q*4] = *(const f32x4*)&xs[mi*196 + c8*24 + q*4];
      int cg = cc*8 + c8;
      float t0 = ths[0*512 + cg*8 + oi];
      float t1 = ths[1*512 + cg*8 + oi];
      float t2 = ths[2*512 + cg*8 + oi];
      #pragma unroll
      for (int t = 0; t < 24; t++){
        acc0[t] = fmaf(t0, xv[t], acc0[t]);
        acc1[t] = fmaf(t1, xv[t], acc1[t]);
        acc2[t] = fmaf(t2, xv[t], acc2[t]);
      }
    }
  }

  // transpose epilogue: per k, stage [192 j][32 p] in LDS then 64B-coalesced stores
  #pragma unroll
  for (int k = 0; k < 3; k++){
    const float* a = (k==0) ? acc0 : (k==1) ? acc1 : acc2;  // unroll-constant select
    __syncthreads();               // ytile reuse across k
    #pragma unroll
    for (int t = 0; t < 24; t++){
      int row = oi*24 + t;
      int sw  = (row >> 3) & 3;
      int sc  = (mi >> 3) ^ sw;            // 16B-chunk swizzle
      ytile[row*32 + sc*8 + (mi & 7)] = f2bf(a[t]);
    }
    __syncthreads();
    for (int r = 0; r < 3; r++){
      int i   = tid + r*256;               // 768 = 192 rows x 4 chunks
      int row = i >> 2, c4 = i & 3;
      int sw  = (row >> 3) & 3;
      uint4 v = *(const uint4*)&ytile[row*32 + (c4 ^ sw)*8];
      size_t ob = ((size_t)bb*JJ + (size_t)jb*192 + row)*PP + k*NN + ms*32 + c4*8;
      *(uint4*)(Yt + ob) = v;
    }
  }
}

// ---------------- K2: per-b GEMM  C[n,j] = relu(sum_p A[p,n]*Y[p,j]), single bf16 ----------------
// UNCHANGED (validated round 3). Tiles: BM=128 x BN=128 x BK=64, 4 waves, 32 KiB LDS,
// global_load_lds with pre-swizzled source (read bank-free).
__global__ __launch_bounds__(256, 2) void kgemm(
    const unsigned short* __restrict__ Ah,
    const unsigned short* __restrict__ Yh,
    float* __restrict__ out, int b0){
  __shared__ unsigned short AsL[128*64];
  __shared__ unsigned short YsL[128*64];
  int orig = blockIdx.x;
  int cpx  = (int)(gridDim.x >> 3);              // grid is NB*96, always % 8 == 0 -> bijective
  int wgid = ((orig & 7) * cpx) + (orig >> 3);   // XCD swizzle
  int bb  = wgid / 96;
  int r96 = wgid - bb*96;
  int nt  = r96 / 12;
  int jt  = r96 - nt*12;
  int tid = threadIdx.x;
  int lane = tid & 63, wave = tid >> 6;
  int wr = wave >> 1, wc = wave & 1;

  unsigned aoff[4], yoff[4];
  #pragma unroll
  for (int it = 0; it < 4; it++){
    int c = tid + it*256;
    int row = c >> 3;
    int sc = (c & 7) ^ (row & 7);
    aoff[it] = (unsigned)(((bb*NN + nt*128 + row) * PP) * 2 + sc * 16);
    yoff[it] = (unsigned)(((bb*JJ + jt*128 + row) * PP) * 2 + sc * 16);
  }

  f32x4 acc[4][4];
  #pragma unroll
  for (int i = 0; i < 4; i++)
    #pragma unroll
    for (int q = 0; q < 4; q++) acc[i][q] = (f32x4){0.f, 0.f, 0.f, 0.f};

  unsigned ldsw = (unsigned)(wave * 1024);
  const char* pA = (const char*)Ah;
  const char* pY = (const char*)Yh;

  for (int ps = 0; ps < PP/64; ps++){
    unsigned so = (unsigned)(ps * 128);
    #pragma unroll
    for (int it = 0; it < 4; it++){
      unsigned ld = ldsw + it*4096;
      __builtin_amdgcn_global_load_lds((gas_cuintp)(pA + aoff[it] + so), (las_uintp)((char*)AsL + ld), 16, 0, 0);
      __builtin_amdgcn_global_load_lds((gas_cuintp)(pY + yoff[it] + so), (las_uintp)((char*)YsL + ld), 16, 0, 0);
    }
    __syncthreads();
    #pragma unroll
    for (int kk = 0; kk < 2; kk++){
      bf16x8 a_f[4], y_f[4];
      #pragma unroll
      for (int i = 0; i < 4; i++){
        int arow = wr*64 + i*16 + (lane & 15);
        int ach  = ((kk*4) + (lane >> 4)) ^ (arow & 7);
        a_f[i] = *(const bf16x8*)&AsL[arow*64 + ach*8];
        int jrow = wc*64 + i*16 + (lane & 15);
        int jch  = ((kk*4) + (lane >> 4)) ^ (jrow & 7);
        y_f[i] = *(const bf16x8*)&YsL[jrow*64 + jch*8];
      }
      #pragma unroll
      for (int i = 0; i < 4; i++)
        #pragma unroll
        for (int q = 0; q < 4; q++)
          acc[i][q] = __builtin_amdgcn_mfma_f32_16x16x32_bf16(a_f[i], y_f[q], acc[i][q], 0, 0, 0);
    }
    __syncthreads();
  }
  size_t ob = (size_t)(b0 + bb) * NN * JJ;
  #pragma unroll
  for (int i = 0; i < 4; i++){
    int nbase = nt*128 + wr*64 + i*16 + ((lane >> 4) << 2);
    #pragma unroll
    for (int q = 0; q < 4; q++){
      int j = jt*128 + wc*64 + q*16 + (lane & 15);
      #pragma unroll
      for (int e = 0; e < 4; e++){
        float v = acc[i][q][e];
        v = v > 0.f ? v : 0.f;
        out[ob + (size_t)(nbase + e) * JJ + j] = v;
      }
    }
  }
}

extern "C" void kernel_launch(void* const* d_in, const int* in_sizes, int n_in,
                              void* d_out, int out_size, void* d_ws, size_t ws_size,
                              hipStream_t stream){
  (void)in_sizes; (void)n_in; (void)out_size;
  const float* x     = (const float*)d_in[0];   // [16][1024][64][24]
  const float* stdg  = (const float*)d_in[1];   // [16][1024][1024]
  const float* cheb  = (const float*)d_in[2];   // [3][1024][1024]
  const float* theta = (const float*)d_in[3];   // [3][64][64]
  float* out = (float*)d_out;                   // [16][1024][64][24] viewed as [16][1024][1536]

  const size_t szA_b = (size_t)NN * PP * sizeof(unsigned short);  // 6.29 MB
  const size_t szY_b = (size_t)PP * JJ * sizeof(unsigned short);  // 9.44 MB
  const size_t per_b = szA_b + szY_b;                             // 15.73 MB
  int NB = 16;
  while (NB > 1 && per_b * (size_t)NB > ws_size) NB >>= 1;        // NB in {16,8,4,2,1}

  char* w = (char*)d_ws;
  unsigned short* Ah = (unsigned short*)w;                         w += szA_b * NB;  // [bb][n][p]
  unsigned short* Yt = (unsigned short*)w;                         w += szY_b * NB;  // [bb][j][p]

  for (int b0 = 0; b0 < BB; b0 += NB){
    kprepA<<<dim3(16, 16),    256, 0, stream>>>(cheb, stdg, Ah, b0, NB);
    kprepY<<<dim3(32, 8, NB), 256, 0, stream>>>(x, theta, Yt, b0);
    kgemm<<<dim3(NB*96),      256, 0, stream>>>(Ah, Yt, out, b0);
  }
}

// Round 6
// 539.679 us; speedup vs baseline: 1.2223x; 1.2223x over previous
//
#include <hip/hip_runtime.h>
#include <stdint.h>

// Chebyshev GCN: out[b,n,o,t] = relu( sum_{k,c,m} cheb[k,m,n]*STDG[b,m,n]*x[b,m,c,t]*theta[k,c,o] )
// Per b:  C[n, j] = relu( sum_p A[p,n] * Y[p,j] ),  p=(k,m) in [0,3072), j=o*24+t
//   A[p,n] = cheb[k,m,n]*STDG[b,m,n]          (kprepA: bf16, stored [bb][n][p])
//   Y[p,j] = sum_c theta[k,c,o]*x[b,m,c,t]    (kprepY: bf16, written transposed [bb][j][p])
// Round-6 change (ONLY kprepY's load scheduling; all addressing/math bit-identical to the
// validated round-5 kernel):
//  - T14 async-STAGE split: round-5 counters showed kprepY latency-bound (VALUBusy 33%,
//    FETCH already at floor after XCD pinning, dur 290us >> 61us fma floor). Each of the 16
//    phases had ~900cy of HBM latency serialized between barriers. Now chunk cc+1's 6 f32x4
//    are prefetched into registers right after chunk cc's ds_writes -> latency hides under
//    the 8-c compute block. Barrier count unchanged.
//  - kprepA / kgemm / launcher: FROZEN (validated rounds 3-5).

#define BB   16
#define NN   1024
#define CIN  64
#define TT   24
#define KCH  3
#define COUT 64
#define PP   (KCH*NN)    // 3072 contraction length
#define JJ   (COUT*TT)   // 1536 output columns per n

typedef __attribute__((ext_vector_type(4))) float f32x4;
typedef __attribute__((ext_vector_type(8))) short bf16x8;

typedef __attribute__((address_space(1))) const unsigned int* gas_cuintp;
typedef __attribute__((address_space(3))) unsigned int* las_uintp;

static __device__ __forceinline__ unsigned short f2bf(float f){
  union { float f; unsigned u; } v; v.f = f;
  unsigned r = v.u + 0x7fffu + ((v.u >> 16) & 1u);   // round-to-nearest-even
  return (unsigned short)(r >> 16);
}

// ---------------- K0: A-prep  (masked = cheb*STDG, bf16, transpose to [bb][n][p]) ----------------
// Grid (16 nt, 16 mt) = 256 blocks; chebT (3 k) staged once; loop over b inside. [validated r5]
__global__ __launch_bounds__(256) void kprepA(const float* __restrict__ cheb,
                                              const float* __restrict__ stdg,
                                              unsigned short* __restrict__ Ah,
                                              int b0, int nb){
  int nt = blockIdx.x;             // 16 n-tiles of 64
  int mt = blockIdx.y;             // 16 m-tiles of 64
  __shared__ float ct[3][64][65];  // chebT [k][n][m], padded (49.9 KB)
  __shared__ float st[64][65];     // stdgT [n][m], padded (16.6 KB)
  int tid = threadIdx.x;
  int rm = tid >> 2;               // m row 0..63 (staging)
  int nc = (tid & 3) << 4;         // n col group
  #pragma unroll
  for (int k = 0; k < 3; k++){
    const float* cp = cheb + ((size_t)(k*NN + mt*64 + rm))*NN + nt*64 + nc;
    #pragma unroll
    for (int i = 0; i < 16; i += 4){
      f32x4 cv = *(const f32x4*)(cp + i);
      #pragma unroll
      for (int q = 0; q < 4; q++) ct[k][nc + i + q][rm] = cv[q];
    }
  }
  int rn = tid >> 2;               // n row 0..63 (compute)
  int mc = (tid & 3) << 4;         // m col group
  for (int bb = 0; bb < nb; bb++){
    int b = b0 + bb;
    __syncthreads();               // ct ready (first iter) / st consumed (later)
    const float* sp = stdg + ((size_t)(b*NN + mt*64 + rm))*NN + nt*64 + nc;
    #pragma unroll
    for (int i = 0; i < 16; i += 4){
      f32x4 sv = *(const f32x4*)(sp + i);
      #pragma unroll
      for (int q = 0; q < 4; q++) st[nc + i + q][rm] = sv[q];
    }
    __syncthreads();
    #pragma unroll
    for (int k = 0; k < 3; k++){
      union { unsigned short s[16]; uint4 v[2]; } hb;
      #pragma unroll
      for (int i = 0; i < 16; i++) hb.s[i] = f2bf(ct[k][rn][mc + i] * st[rn][mc + i]);
      size_t ob = ((size_t)(bb*NN + nt*64 + rn))*PP + (size_t)k*NN + mt*64 + mc;
      *(uint4*)(Ah + ob)     = hb.v[0];
      *(uint4*)(Ah + ob + 8) = hb.v[1];
    }
  }
}

// ---------------- K1: Y-prep fused with transpose -> writes [bb][j][p] directly ----------------
// Addressing/math identical to validated round-5 body; ONLY change: T14 prefetch of the next
// c-chunk into registers (pf[6]) issued right after the current chunk's ds_writes, so the 16
// staging phases' HBM latency hides under compute. Grid: ms = blockIdx.x (XCD pin), jb = y.
__global__ __launch_bounds__(256) void kprepY(const float* __restrict__ x,
                                              const float* __restrict__ theta,
                                              unsigned short* __restrict__ Yt,
                                              int b0){
  int ms = blockIdx.x;             // 32 m-slabs of 32
  int jb = blockIdx.y;             // 8 o-blocks of 8
  int bb = blockIdx.z;
  int b  = b0 + bb;
  __shared__ float xs[32*196];             // 25088 B (per-m stride 196 floats, 192 used)
  __shared__ float ths[3*64*8];            // 6144 B
  __shared__ unsigned short ytile[192*32]; // 12288 B
  int tid = threadIdx.x;
  int mi = tid >> 3, oi = tid & 7;

  // stage theta slice [3][64 c][8 o]
  for (int i = tid; i < 3*64*8; i += 256){
    int k = i >> 9, rem = i & 511;
    int c = rem >> 3, o = rem & 7;
    ths[i] = theta[k*(CIN*COUT) + c*COUT + jb*8 + o];
  }

  float acc0[24], acc1[24], acc2[24];
  #pragma unroll
  for (int t = 0; t < 24; t++){ acc0[t]=0.f; acc1[t]=0.f; acc2[t]=0.f; }

  const f32x4* xg4 = (const f32x4*)(x + ((size_t)(b*NN + ms*32))*CIN*TT);

  // per-thread staging slots (fixed across chunks): i4 = tid + u*256, u = 0..5
  int pm[6], pr[6];
  #pragma unroll
  for (int u = 0; u < 6; u++){
    int i4 = tid + u*256;
    pm[u] = i4 / 48; pr[u] = i4 - pm[u]*48;
  }
  // prefetch chunk 0
  f32x4 pf[6];
  #pragma unroll
  for (int u = 0; u < 6; u++) pf[u] = xg4[pm[u]*384 + pr[u]];

  for (int cc = 0; cc < 8; cc++){
    __syncthreads();               // first iter: theta ready; later: xs consumed
    #pragma unroll
    for (int u = 0; u < 6; u++) *(f32x4*)&xs[pm[u]*196 + pr[u]*4] = pf[u];
    __syncthreads();
    if (cc < 7){                   // issue NEXT chunk's loads; they fly under the compute below
      #pragma unroll
      for (int u = 0; u < 6; u++) pf[u] = xg4[pm[u]*384 + (cc+1)*48 + pr[u]];
    }
    for (int c8 = 0; c8 < 8; c8++){
      float xv[24];
      #pragma unroll
      for (int q = 0; q < 6; q++) *(f32x4*)&xv[q*4] = *(const f32x4*)&xs[mi*196 + c8*24 + q*4];
      int cg = cc*8 + c8;
      float t0 = ths[0*512 + cg*8 + oi];
      float t1 = ths[1*512 + cg*8 + oi];
      float t2 = ths[2*512 + cg*8 + oi];
      #pragma unroll
      for (int t = 0; t < 24; t++){
        acc0[t] = fmaf(t0, xv[t], acc0[t]);
        acc1[t] = fmaf(t1, xv[t], acc1[t]);
        acc2[t] = fmaf(t2, xv[t], acc2[t]);
      }
    }
  }

  // transpose epilogue: per k, stage [192 j][32 p] in LDS then 64B-coalesced stores [validated]
  #pragma unroll
  for (int k = 0; k < 3; k++){
    const float* a = (k==0) ? acc0 : (k==1) ? acc1 : acc2;  // unroll-constant select
    __syncthreads();               // ytile reuse across k
    #pragma unroll
    for (int t = 0; t < 24; t++){
      int row = oi*24 + t;
      int sw  = (row >> 3) & 3;
      int sc  = (mi >> 3) ^ sw;            // 16B-chunk swizzle
      ytile[row*32 + sc*8 + (mi & 7)] = f2bf(a[t]);
    }
    __syncthreads();
    for (int r = 0; r < 3; r++){
      int i   = tid + r*256;               // 768 = 192 rows x 4 chunks
      int row = i >> 2, c4 = i & 3;
      int sw  = (row >> 3) & 3;
      uint4 v = *(const uint4*)&ytile[row*32 + (c4 ^ sw)*8];
      size_t ob = ((size_t)bb*JJ + (size_t)jb*192 + row)*PP + k*NN + ms*32 + c4*8;
      *(uint4*)(Yt + ob) = v;
    }
  }
}

// ---------------- K2: per-b GEMM  C[n,j] = relu(sum_p A[p,n]*Y[p,j]), single bf16 ----------------
// UNCHANGED (validated rounds 3/5). BM=128 x BN=128 x BK=64, 4 waves, 32 KiB LDS,
// global_load_lds with pre-swizzled source (read bank-free).
__global__ __launch_bounds__(256, 2) void kgemm(
    const unsigned short* __restrict__ Ah,
    const unsigned short* __restrict__ Yh,
    float* __restrict__ out, int b0){
  __shared__ unsigned short AsL[128*64];
  __shared__ unsigned short YsL[128*64];
  int orig = blockIdx.x;
  int cpx  = (int)(gridDim.x >> 3);              // grid is NB*96, always % 8 == 0 -> bijective
  int wgid = ((orig & 7) * cpx) + (orig >> 3);   // XCD swizzle
  int bb  = wgid / 96;
  int r96 = wgid - bb*96;
  int nt  = r96 / 12;
  int jt  = r96 - nt*12;
  int tid = threadIdx.x;
  int lane = tid & 63, wave = tid >> 6;
  int wr = wave >> 1, wc = wave & 1;

  unsigned aoff[4], yoff[4];
  #pragma unroll
  for (int it = 0; it < 4; it++){
    int c = tid + it*256;
    int row = c >> 3;
    int sc = (c & 7) ^ (row & 7);
    aoff[it] = (unsigned)(((bb*NN + nt*128 + row) * PP) * 2 + sc * 16);
    yoff[it] = (unsigned)(((bb*JJ + jt*128 + row) * PP) * 2 + sc * 16);
  }

  f32x4 acc[4][4];
  #pragma unroll
  for (int i = 0; i < 4; i++)
    #pragma unroll
    for (int q = 0; q < 4; q++) acc[i][q] = (f32x4){0.f, 0.f, 0.f, 0.f};

  unsigned ldsw = (unsigned)(wave * 1024);
  const char* pA = (const char*)Ah;
  const char* pY = (const char*)Yh;

  for (int ps = 0; ps < PP/64; ps++){
    unsigned so = (unsigned)(ps * 128);
    #pragma unroll
    for (int it = 0; it < 4; it++){
      unsigned ld = ldsw + it*4096;
      __builtin_amdgcn_global_load_lds((gas_cuintp)(pA + aoff[it] + so), (las_uintp)((char*)AsL + ld), 16, 0, 0);
      __builtin_amdgcn_global_load_lds((gas_cuintp)(pY + yoff[it] + so), (las_uintp)((char*)YsL + ld), 16, 0, 0);
    }
    __syncthreads();
    #pragma unroll
    for (int kk = 0; kk < 2; kk++){
      bf16x8 a_f[4], y_f[4];
      #pragma unroll
      for (int i = 0; i < 4; i++){
        int arow = wr*64 + i*16 + (lane & 15);
        int ach  = ((kk*4) + (lane >> 4)) ^ (arow & 7);
        a_f[i] = *(const bf16x8*)&AsL[arow*64 + ach*8];
        int jrow = wc*64 + i*16 + (lane & 15);
        int jch  = ((kk*4) + (lane >> 4)) ^ (jrow & 7);
        y_f[i] = *(const bf16x8*)&YsL[jrow*64 + jch*8];
      }
      #pragma unroll
      for (int i = 0; i < 4; i++)
        #pragma unroll
        for (int q = 0; q < 4; q++)
          acc[i][q] = __builtin_amdgcn_mfma_f32_16x16x32_bf16(a_f[i], y_f[q], acc[i][q], 0, 0, 0);
    }
    __syncthreads();
  }
  size_t ob = (size_t)(b0 + bb) * NN * JJ;
  #pragma unroll
  for (int i = 0; i < 4; i++){
    int nbase = nt*128 + wr*64 + i*16 + ((lane >> 4) << 2);
    #pragma unroll
    for (int q = 0; q < 4; q++){
      int j = jt*128 + wc*64 + q*16 + (lane & 15);
      #pragma unroll
      for (int e = 0; e < 4; e++){
        float v = acc[i][q][e];
        v = v > 0.f ? v : 0.f;
        out[ob + (size_t)(nbase + e) * JJ + j] = v;
      }
    }
  }
}

extern "C" void kernel_launch(void* const* d_in, const int* in_sizes, int n_in,
                              void* d_out, int out_size, void* d_ws, size_t ws_size,
                              hipStream_t stream){
  (void)in_sizes; (void)n_in; (void)out_size;
  const float* x     = (const float*)d_in[0];   // [16][1024][64][24]
  const float* stdg  = (const float*)d_in[1];   // [16][1024][1024]
  const float* cheb  = (const float*)d_in[2];   // [3][1024][1024]
  const float* theta = (const float*)d_in[3];   // [3][64][64]
  float* out = (float*)d_out;                   // [16][1024][64][24] viewed as [16][1024][1536]

  const size_t szA_b = (size_t)NN * PP * sizeof(unsigned short);  // 6.29 MB
  const size_t szY_b = (size_t)PP * JJ * sizeof(unsigned short);  // 9.44 MB
  const size_t per_b = szA_b + szY_b;                             // 15.73 MB
  int NB = 16;
  while (NB > 1 && per_b * (size_t)NB > ws_size) NB >>= 1;        // NB in {16,8,4,2,1}

  char* w = (char*)d_ws;
  unsigned short* Ah = (unsigned short*)w;                         w += szA_b * NB;  // [bb][n][p]
  unsigned short* Yt = (unsigned short*)w;                         w += szY_b * NB;  // [bb][j][p]

  for (int b0 = 0; b0 < BB; b0 += NB){
    kprepA<<<dim3(16, 16),    256, 0, stream>>>(cheb, stdg, Ah, b0, NB);
    kprepY<<<dim3(32, 8, NB), 256, 0, stream>>>(x, theta, Yt, b0);
    kgemm<<<dim3(NB*96),      256, 0, stream>>>(Ah, Yt, out, b0);
  }
}